// Round 1
// baseline (755.848 us; speedup 1.0000x reference)
//
#include <hip/hip_runtime.h>

#define H_ 1024
#define W_ 1024
#define RAD 30
#define EPSF 1.3f
#define SEG 64

// padded index for LDS prefix arrays: breaks the stride-4-float bank pattern
__device__ __forceinline__ int padidx(int i) { return i + (i >> 3); }
#define PREF_SZ ((W_ + 1) + ((W_ + 1) >> 3) + 1)

// ---------------------------------------------------------------------------
// K1/K3: per-row horizontal clipped-window sums via block prefix scan.
// MODE 0: in0=R, in1=I -> fields {R, I, R*I, R*R} to o0..o3
// MODE 1: in0=a, in1=b -> fields {a, b} to o0..o1
// One block per row (1024 elems), 256 threads x 4 elems.
// ---------------------------------------------------------------------------
template <int MODE>
__global__ __launch_bounds__(256)
void hsum_kernel(const float* __restrict__ in0, const float* __restrict__ in1,
                 long long in_off,
                 float* __restrict__ o0, float* __restrict__ o1,
                 float* __restrict__ o2, float* __restrict__ o3)
{
    constexpr int NF = (MODE == 0) ? 4 : 2;
    __shared__ float pref[NF][PREF_SZ];
    __shared__ float sbuf[NF][256];

    const int tid = threadIdx.x;
    const long long base = (long long)blockIdx.x * W_;
    const int x0 = tid * 4;

    const float4 a4 = *(const float4*)(in0 + in_off + base + x0);
    const float4 b4 = *(const float4*)(in1 + in_off + base + x0);
    const float av[4] = {a4.x, a4.y, a4.z, a4.w};
    const float bv[4] = {b4.x, b4.y, b4.z, b4.w};

    float f[NF][4];
#pragma unroll
    for (int j = 0; j < 4; ++j) {
        f[0][j] = av[j];
        f[1][j] = bv[j];
        if (MODE == 0) {
            f[2][j] = av[j] * bv[j];
            f[3][j] = av[j] * av[j];
        }
    }

    // per-thread local inclusive scan + thread totals
    float loc[NF][4], tot[NF];
#pragma unroll
    for (int ff = 0; ff < NF; ++ff) {
        loc[ff][0] = f[ff][0];
#pragma unroll
        for (int j = 1; j < 4; ++j) loc[ff][j] = loc[ff][j - 1] + f[ff][j];
        tot[ff] = loc[ff][3];
    }

    // block-wide Hillis-Steele inclusive scan of thread totals
#pragma unroll
    for (int ff = 0; ff < NF; ++ff) sbuf[ff][tid] = tot[ff];
    __syncthreads();
#pragma unroll
    for (int off = 1; off < 256; off <<= 1) {
        float t[NF];
#pragma unroll
        for (int ff = 0; ff < NF; ++ff) t[ff] = (tid >= off) ? sbuf[ff][tid - off] : 0.0f;
        __syncthreads();
#pragma unroll
        for (int ff = 0; ff < NF; ++ff) sbuf[ff][tid] += t[ff];
        __syncthreads();
    }
    float ex[NF];
#pragma unroll
    for (int ff = 0; ff < NF; ++ff) ex[ff] = sbuf[ff][tid] - tot[ff];

    // write inclusive prefix (with leading zero) into padded LDS array
#pragma unroll
    for (int ff = 0; ff < NF; ++ff) {
#pragma unroll
        for (int j = 0; j < 4; ++j)
            pref[ff][padidx(x0 + 1 + j)] = ex[ff] + loc[ff][j];
    }
    if (tid == 0) {
#pragma unroll
        for (int ff = 0; ff < NF; ++ff) pref[ff][padidx(0)] = 0.0f;
    }
    __syncthreads();

    // window sums: sum over [x-RAD, x+RAD] clipped = pref[hi] - pref[lo]
    float res[NF][4];
#pragma unroll
    for (int j = 0; j < 4; ++j) {
        const int x = x0 + j;
        const int hi = min(x + RAD + 1, W_);
        const int lo = max(x - RAD, 0);
#pragma unroll
        for (int ff = 0; ff < NF; ++ff)
            res[ff][j] = pref[ff][padidx(hi)] - pref[ff][padidx(lo)];
    }

    float* const outs[4] = {o0, o1, o2, o3};
#pragma unroll
    for (int ff = 0; ff < NF; ++ff) {
        *(float4*)(outs[ff] + base + x0) =
            make_float4(res[ff][0], res[ff][1], res[ff][2], res[ff][3]);
    }
}

// ---------------------------------------------------------------------------
// K2: vertical sliding-window sums of {hR,hI,hRI,hRR}; compute a, b.
// grid = (W/256, H/SEG, planes_in_chunk); one thread per column.
// ---------------------------------------------------------------------------
__global__ __launch_bounds__(256)
void vsum_ab_kernel(const float* __restrict__ hR, const float* __restrict__ hI,
                    const float* __restrict__ hRI, const float* __restrict__ hRR,
                    float* __restrict__ A, float* __restrict__ Bv)
{
    const int x = blockIdx.x * 256 + threadIdx.x;
    const int y0 = blockIdx.y * SEG;
    const long long pb = (long long)blockIdx.z * ((long long)H_ * W_);

    float sR = 0.f, sI = 0.f, sRI = 0.f, sRR = 0.f;
    const int ylo = max(0, y0 - RAD), yhi = min(H_ - 1, y0 + RAD);
    for (int yy = ylo; yy <= yhi; ++yy) {
        const long long o = pb + (long long)yy * W_ + x;
        sR += hR[o]; sI += hI[o]; sRI += hRI[o]; sRR += hRR[o];
    }
    const float cntx = (float)(min(x + RAD, W_ - 1) - max(x - RAD, 0) + 1);
    const int yend = min(H_, y0 + SEG);
    for (int y = y0; y < yend; ++y) {
        const float cnty = (float)(min(y + RAD, H_ - 1) - max(y - RAD, 0) + 1);
        const float invN = 1.0f / (cntx * cnty);
        const float mR = sR * invN, mI = sI * invN;
        const float a = (sRI * invN - mR * mI) / (sRR * invN - mR * mR + EPSF);
        const float b = mI - a * mR;
        const long long o = pb + (long long)y * W_ + x;
        A[o] = a;
        Bv[o] = b;
        const int ya = y + RAD + 1, ys = y - RAD;
        if (ya < H_) {
            const long long oa = pb + (long long)ya * W_ + x;
            sR += hR[oa]; sI += hI[oa]; sRI += hRI[oa]; sRR += hRR[oa];
        }
        if (ys >= 0) {
            const long long os = pb + (long long)ys * W_ + x;
            sR -= hR[os]; sI -= hI[os]; sRI -= hRI[os]; sRR -= hRR[os];
        }
    }
}

// ---------------------------------------------------------------------------
// K4: vertical sliding-window sums of {ha,hb}; out = mean_a * R + mean_b.
// ---------------------------------------------------------------------------
__global__ __launch_bounds__(256)
void vsum_final_kernel(const float* __restrict__ hA, const float* __restrict__ hB,
                       const float* __restrict__ Rimg, long long in_off,
                       float* __restrict__ out)
{
    const int x = blockIdx.x * 256 + threadIdx.x;
    const int y0 = blockIdx.y * SEG;
    const long long pb = (long long)blockIdx.z * ((long long)H_ * W_);

    float sA = 0.f, sB = 0.f;
    const int ylo = max(0, y0 - RAD), yhi = min(H_ - 1, y0 + RAD);
    for (int yy = ylo; yy <= yhi; ++yy) {
        const long long o = pb + (long long)yy * W_ + x;
        sA += hA[o]; sB += hB[o];
    }
    const float cntx = (float)(min(x + RAD, W_ - 1) - max(x - RAD, 0) + 1);
    const int yend = min(H_, y0 + SEG);
    for (int y = y0; y < yend; ++y) {
        const float cnty = (float)(min(y + RAD, H_ - 1) - max(y - RAD, 0) + 1);
        const float invN = 1.0f / (cntx * cnty);
        const long long o = pb + (long long)y * W_ + x;
        out[in_off + o] = (sA * invN) * Rimg[in_off + o] + sB * invN;
        const int ya = y + RAD + 1, ys = y - RAD;
        if (ya < H_) {
            const long long oa = pb + (long long)ya * W_ + x;
            sA += hA[oa]; sB += hB[oa];
        }
        if (ys >= 0) {
            const long long os = pb + (long long)ys * W_ + x;
            sA -= hA[os]; sB -= hB[os];
        }
    }
}

// ---------------------------------------------------------------------------
extern "C" void kernel_launch(void* const* d_in, const int* in_sizes, int n_in,
                              void* d_out, int out_size, void* d_ws, size_t ws_size,
                              hipStream_t stream)
{
    const float* I = (const float*)d_in[0];   // image to filter
    const float* R = (const float*)d_in[1];   // guidance image
    float* out = (float*)d_out;

    const long long plane = (long long)H_ * W_;
    const int P = (int)(in_sizes[0] / plane);             // 24 planes
    const size_t arr_pb = (size_t)plane * sizeof(float);  // 4 MB per plane per array

    int CHUNK = (int)(ws_size / (6 * arr_pb));
    if (CHUNK > 8) CHUNK = 8;   // keep chunk working set L3-resident
    if (CHUNK > P) CHUNK = P;
    if (CHUNK < 1) CHUNK = 1;

    const size_t astride = (size_t)CHUNK * plane;  // floats per scratch array
    float* w = (float*)d_ws;
    float* ws0 = w;
    float* ws1 = ws0 + astride;
    float* ws2 = ws1 + astride;
    float* ws3 = ws2 + astride;
    float* ws4 = ws3 + astride;
    float* ws5 = ws4 + astride;

    for (int p0 = 0; p0 < P; p0 += CHUNK) {
        const int pc = (P - p0 < CHUNK) ? (P - p0) : CHUNK;
        const long long in_off = (long long)p0 * plane;
        const dim3 g2(W_ / 256, H_ / SEG, pc);

        // K1: horizontal sums of {R, I, RI, RR}
        hipLaunchKernelGGL((hsum_kernel<0>), dim3(pc * H_), dim3(256), 0, stream,
                           R, I, in_off, ws0, ws1, ws2, ws3);
        // K2: vertical sums -> a, b
        hipLaunchKernelGGL(vsum_ab_kernel, g2, dim3(256), 0, stream,
                           ws0, ws1, ws2, ws3, ws4, ws5);
        // K3: horizontal sums of {a, b} (reuse ws0, ws1)
        hipLaunchKernelGGL((hsum_kernel<1>), dim3(pc * H_), dim3(256), 0, stream,
                           ws4, ws5, 0LL, ws0, ws1, ws2, ws3);
        // K4: vertical sums of {ha, hb} + final combine with R
        hipLaunchKernelGGL(vsum_final_kernel, g2, dim3(256), 0, stream,
                           ws0, ws1, R, in_off, out);
    }
}

// Round 2
// 532.034 us; speedup vs baseline: 1.4207x; 1.4207x over previous
//
#include <hip/hip_runtime.h>

#define H_ 1024
#define W_ 1024
#define RAD 30
#define EPSF 1.3f
#define VSEG 32   // rows per vertical-kernel block segment

// padded index for LDS prefix arrays: breaks the stride-4-float bank pattern
__device__ __forceinline__ int padidx(int i) { return i + (i >> 3); }
#define PREF_SZ ((W_ + 1) + ((W_ + 1) >> 3) + 1)

// ---------------------------------------------------------------------------
// A: vertical sliding-window sums of {R, I, R*I, R*R} straight from inputs.
// grid = (W/256, H/VSEG, pc); one thread per column.
// Sliding re-reads touch only the (L2/L3-warm) input planes.
// ---------------------------------------------------------------------------
__global__ __launch_bounds__(256)
void vert_in_kernel(const float* __restrict__ I, const float* __restrict__ R,
                    long long in_off,
                    float* __restrict__ vR, float* __restrict__ vI,
                    float* __restrict__ vRI, float* __restrict__ vRR)
{
    const int x = blockIdx.x * 256 + threadIdx.x;
    const int y0 = blockIdx.y * VSEG;
    const long long pb = (long long)blockIdx.z * ((long long)H_ * W_);
    const long long ib = in_off + pb;

    float sR = 0.f, sI = 0.f, sRI = 0.f, sRR = 0.f;
    const int ylo = max(0, y0 - RAD), yhi = min(H_ - 1, y0 + RAD);
    for (int yy = ylo; yy <= yhi; ++yy) {
        const long long o = ib + (long long)yy * W_ + x;
        const float r = R[o], i = I[o];
        sR += r; sI += i; sRI += r * i; sRR += r * r;
    }
    const int yend = y0 + VSEG;
    for (int y = y0; y < yend; ++y) {
        const long long o = pb + (long long)y * W_ + x;
        vR[o] = sR; vI[o] = sI; vRI[o] = sRI; vRR[o] = sRR;
        const int ya = y + RAD + 1, ys = y - RAD;
        if (ya < H_) {
            const long long oa = ib + (long long)ya * W_ + x;
            const float r = R[oa], i = I[oa];
            sR += r; sI += i; sRI += r * i; sRR += r * r;
        }
        if (ys >= 0) {
            const long long os = ib + (long long)ys * W_ + x;
            const float r = R[os], i = I[os];
            sR -= r; sI -= i; sRI -= r * i; sRR -= r * r;
        }
    }
}

// ---------------------------------------------------------------------------
// B: per-row horizontal prefix scan (shfl wave-scan) of the 4 v-fields ->
// full box sums -> solve a = cov/(var+eps), b = mI - a*mR. Writes a, b.
// One block per (plane-row); 256 threads x 4 px.
// ---------------------------------------------------------------------------
__global__ __launch_bounds__(256)
void hsolve_kernel(const float* __restrict__ vR, const float* __restrict__ vI,
                   const float* __restrict__ vRI, const float* __restrict__ vRR,
                   float* __restrict__ A, float* __restrict__ Bv)
{
    __shared__ float pref[4][PREF_SZ];
    __shared__ float wsum[4][4];

    const int tid = threadIdx.x;
    const int lane = tid & 63, wid = tid >> 6;
    const int y = blockIdx.x % H_;
    const long long base = (long long)blockIdx.x * W_;
    const int x0 = tid * 4;

    const float4 r4 = *(const float4*)(vR + base + x0);
    const float4 i4 = *(const float4*)(vI + base + x0);
    const float4 p4 = *(const float4*)(vRI + base + x0);
    const float4 q4 = *(const float4*)(vRR + base + x0);
    float f[4][4] = {{r4.x, r4.y, r4.z, r4.w},
                     {i4.x, i4.y, i4.z, i4.w},
                     {p4.x, p4.y, p4.z, p4.w},
                     {q4.x, q4.y, q4.z, q4.w}};

    float loc[4][4], tot[4];
#pragma unroll
    for (int ff = 0; ff < 4; ++ff) {
        loc[ff][0] = f[ff][0];
#pragma unroll
        for (int j = 1; j < 4; ++j) loc[ff][j] = loc[ff][j - 1] + f[ff][j];
        tot[ff] = loc[ff][3];
    }

    // wave-inclusive scan of thread totals (no barriers)
    float ws[4];
#pragma unroll
    for (int ff = 0; ff < 4; ++ff) {
        float s = tot[ff];
#pragma unroll
        for (int d = 1; d < 64; d <<= 1) {
            float t = __shfl_up(s, d, 64);
            if (lane >= d) s += t;
        }
        ws[ff] = s;
        if (lane == 63) wsum[ff][wid] = s;
    }
    __syncthreads();

    float woff[4] = {0.f, 0.f, 0.f, 0.f};
#pragma unroll
    for (int ff = 0; ff < 4; ++ff)
        for (int w = 0; w < 4; ++w)
            if (w < wid) woff[ff] += wsum[ff][w];

#pragma unroll
    for (int ff = 0; ff < 4; ++ff) {
        const float ex = woff[ff] + ws[ff] - tot[ff];  // exclusive prefix at x0
#pragma unroll
        for (int j = 0; j < 4; ++j)
            pref[ff][padidx(x0 + 1 + j)] = ex + loc[ff][j];
    }
    if (tid == 0) {
#pragma unroll
        for (int ff = 0; ff < 4; ++ff) pref[ff][padidx(0)] = 0.0f;
    }
    __syncthreads();

    const float cnty = (float)(min(y + RAD, H_ - 1) - max(y - RAD, 0) + 1);
    float av[4], bv[4];
#pragma unroll
    for (int j = 0; j < 4; ++j) {
        const int x = x0 + j;
        const int hi = padidx(min(x + RAD + 1, W_));
        const int lo = padidx(max(x - RAD, 0));
        const float SR = pref[0][hi] - pref[0][lo];
        const float SI = pref[1][hi] - pref[1][lo];
        const float SP = pref[2][hi] - pref[2][lo];
        const float SQ = pref[3][hi] - pref[3][lo];
        const float cntx = (float)(min(x + RAD, W_ - 1) - max(x - RAD, 0) + 1);
        const float invN = 1.0f / (cntx * cnty);
        const float mR = SR * invN, mI = SI * invN;
        const float a = (SP * invN - mR * mI) / (SQ * invN - mR * mR + EPSF);
        av[j] = a;
        bv[j] = mI - a * mR;
    }
    *(float4*)(A + base + x0) = make_float4(av[0], av[1], av[2], av[3]);
    *(float4*)(Bv + base + x0) = make_float4(bv[0], bv[1], bv[2], bv[3]);
}

// ---------------------------------------------------------------------------
// C: vertical sliding-window sums of {a, b}.
// ---------------------------------------------------------------------------
__global__ __launch_bounds__(256)
void vert_ab_kernel(const float* __restrict__ A, const float* __restrict__ Bv,
                    float* __restrict__ vA, float* __restrict__ vB)
{
    const int x = blockIdx.x * 256 + threadIdx.x;
    const int y0 = blockIdx.y * VSEG;
    const long long pb = (long long)blockIdx.z * ((long long)H_ * W_);

    float sA = 0.f, sB = 0.f;
    const int ylo = max(0, y0 - RAD), yhi = min(H_ - 1, y0 + RAD);
    for (int yy = ylo; yy <= yhi; ++yy) {
        const long long o = pb + (long long)yy * W_ + x;
        sA += A[o]; sB += Bv[o];
    }
    const int yend = y0 + VSEG;
    for (int y = y0; y < yend; ++y) {
        const long long o = pb + (long long)y * W_ + x;
        vA[o] = sA; vB[o] = sB;
        const int ya = y + RAD + 1, ys = y - RAD;
        if (ya < H_) {
            const long long oa = pb + (long long)ya * W_ + x;
            sA += A[oa]; sB += Bv[oa];
        }
        if (ys >= 0) {
            const long long os = pb + (long long)ys * W_ + x;
            sA -= A[os]; sB -= Bv[os];
        }
    }
}

// ---------------------------------------------------------------------------
// D: per-row horizontal scan of {va, vb} -> box means -> out = ma*R + mb.
// ---------------------------------------------------------------------------
__global__ __launch_bounds__(256)
void hfinal_kernel(const float* __restrict__ vA, const float* __restrict__ vB,
                   const float* __restrict__ Rimg, long long in_off,
                   float* __restrict__ out)
{
    __shared__ float pref[2][PREF_SZ];
    __shared__ float wsum[2][4];

    const int tid = threadIdx.x;
    const int lane = tid & 63, wid = tid >> 6;
    const int y = blockIdx.x % H_;
    const long long base = (long long)blockIdx.x * W_;
    const int x0 = tid * 4;

    const float4 a4 = *(const float4*)(vA + base + x0);
    const float4 b4 = *(const float4*)(vB + base + x0);
    float f[2][4] = {{a4.x, a4.y, a4.z, a4.w},
                     {b4.x, b4.y, b4.z, b4.w}};

    float loc[2][4], tot[2];
#pragma unroll
    for (int ff = 0; ff < 2; ++ff) {
        loc[ff][0] = f[ff][0];
#pragma unroll
        for (int j = 1; j < 4; ++j) loc[ff][j] = loc[ff][j - 1] + f[ff][j];
        tot[ff] = loc[ff][3];
    }

    float ws[2];
#pragma unroll
    for (int ff = 0; ff < 2; ++ff) {
        float s = tot[ff];
#pragma unroll
        for (int d = 1; d < 64; d <<= 1) {
            float t = __shfl_up(s, d, 64);
            if (lane >= d) s += t;
        }
        ws[ff] = s;
        if (lane == 63) wsum[ff][wid] = s;
    }
    __syncthreads();

    float woff[2] = {0.f, 0.f};
#pragma unroll
    for (int ff = 0; ff < 2; ++ff)
        for (int w = 0; w < 4; ++w)
            if (w < wid) woff[ff] += wsum[ff][w];

#pragma unroll
    for (int ff = 0; ff < 2; ++ff) {
        const float ex = woff[ff] + ws[ff] - tot[ff];
#pragma unroll
        for (int j = 0; j < 4; ++j)
            pref[ff][padidx(x0 + 1 + j)] = ex + loc[ff][j];
    }
    if (tid == 0) {
#pragma unroll
        for (int ff = 0; ff < 2; ++ff) pref[ff][padidx(0)] = 0.0f;
    }
    __syncthreads();

    const float cnty = (float)(min(y + RAD, H_ - 1) - max(y - RAD, 0) + 1);
    const float4 r4 = *(const float4*)(Rimg + in_off + base + x0);
    const float rv[4] = {r4.x, r4.y, r4.z, r4.w};
    float ov[4];
#pragma unroll
    for (int j = 0; j < 4; ++j) {
        const int x = x0 + j;
        const int hi = padidx(min(x + RAD + 1, W_));
        const int lo = padidx(max(x - RAD, 0));
        const float SA = pref[0][hi] - pref[0][lo];
        const float SB = pref[1][hi] - pref[1][lo];
        const float cntx = (float)(min(x + RAD, W_ - 1) - max(x - RAD, 0) + 1);
        const float invN = 1.0f / (cntx * cnty);
        ov[j] = (SA * invN) * rv[j] + SB * invN;
    }
    *(float4*)(out + in_off + base + x0) = make_float4(ov[0], ov[1], ov[2], ov[3]);
}

// ---------------------------------------------------------------------------
extern "C" void kernel_launch(void* const* d_in, const int* in_sizes, int n_in,
                              void* d_out, int out_size, void* d_ws, size_t ws_size,
                              hipStream_t stream)
{
    const float* I = (const float*)d_in[0];   // image to filter
    const float* R = (const float*)d_in[1];   // guidance image
    float* out = (float*)d_out;

    const long long plane = (long long)H_ * W_;
    const int P = (int)(in_sizes[0] / plane);             // 24 planes
    const size_t arr_pb = (size_t)plane * sizeof(float);  // 4 MB per plane per array

    int CHUNK = (int)(ws_size / (6 * arr_pb));
    if (CHUNK > 8) CHUNK = 8;   // keep chunk working set ~L3-resident
    if (CHUNK > P) CHUNK = P;
    if (CHUNK < 1) CHUNK = 1;

    const size_t astride = (size_t)CHUNK * plane;
    float* w = (float*)d_ws;
    float* ws0 = w;
    float* ws1 = ws0 + astride;
    float* ws2 = ws1 + astride;
    float* ws3 = ws2 + astride;
    float* ws4 = ws3 + astride;
    float* ws5 = ws4 + astride;

    for (int p0 = 0; p0 < P; p0 += CHUNK) {
        const int pc = (P - p0 < CHUNK) ? (P - p0) : CHUNK;
        const long long in_off = (long long)p0 * plane;
        const dim3 gv(W_ / 256, H_ / VSEG, pc);
        const dim3 gh(pc * H_);

        // A: vertical sums of {R, I, RI, RR} from inputs
        hipLaunchKernelGGL(vert_in_kernel, gv, dim3(256), 0, stream,
                           I, R, in_off, ws0, ws1, ws2, ws3);
        // B: horizontal scan + solve -> a, b
        hipLaunchKernelGGL(hsolve_kernel, gh, dim3(256), 0, stream,
                           ws0, ws1, ws2, ws3, ws4, ws5);
        // C: vertical sums of {a, b}
        hipLaunchKernelGGL(vert_ab_kernel, gv, dim3(256), 0, stream,
                           ws4, ws5, ws0, ws1);
        // D: horizontal scan of {va, vb} + combine with R -> out
        hipLaunchKernelGGL(hfinal_kernel, gh, dim3(256), 0, stream,
                           ws0, ws1, R, in_off, out);
    }
}

// Round 3
// 379.238 us; speedup vs baseline: 1.9931x; 1.4029x over previous
//
#include <hip/hip_runtime.h>

#define H_ 1024
#define W_ 1024
#define RAD 30
#define EPSF 1.3f
#define SH 32            // output rows per block
#define NSEG (H_ / SH)   // 32 y-segments

// padded LDS index: breaks stride-4-float bank pattern on prefix reads
__device__ __forceinline__ int padidx(int i) { return i + (i >> 3); }
#define PSZ (W_ + (W_ >> 3) + 1)   // padidx(1024)=1152 -> 1153 entries

// ---------------------------------------------------------------------------
// fused_ab: per (plane, 32-row segment) block. Vertical sliding sums of
// {R, I, R*I, R*R} in registers (4 cols/thread, full 1024-wide row => no
// x-halo); per output row an in-LDS horizontal prefix scan gives the full
// 2D box sums; solve a = cov/(var+eps), b = mI - a*mR; write only a, b.
// ---------------------------------------------------------------------------
__global__ __launch_bounds__(256)
void fused_ab(const float* __restrict__ I, const float* __restrict__ R,
              long long in_off, float* __restrict__ A, float* __restrict__ Bv)
{
    __shared__ float P[2][4][PSZ];   // double-buffered prefix arrays
    __shared__ float wt[2][4][4];    // per-wave totals

    const int tid = threadIdx.x;
    const int lane = tid & 63, wid = tid >> 6;
    const int x0 = tid * 4;
    const int y0 = blockIdx.x * SH;
    const long long pb = (long long)blockIdx.y * (long long)(H_ * W_);
    const long long ib = in_off + pb;

    float icx[4];
#pragma unroll
    for (int j = 0; j < 4; ++j) {
        const int x = x0 + j;
        icx[j] = 1.0f / (float)(min(x + RAD, W_ - 1) - max(x - RAD, 0) + 1);
    }

    float s[4][4];   // running vertical sums: [field][col]
#pragma unroll
    for (int f = 0; f < 4; ++f)
#pragma unroll
        for (int j = 0; j < 4; ++j) s[f][j] = 0.0f;

    // warm-up: rows [y0-RAD, y0+RAD] clipped
    {
        const int ylo = max(0, y0 - RAD), yhi = min(H_ - 1, y0 + RAD);
        for (int yy = ylo; yy <= yhi; ++yy) {
            const float4 r4 = *(const float4*)(R + ib + (long long)yy * W_ + x0);
            const float4 i4 = *(const float4*)(I + ib + (long long)yy * W_ + x0);
            const float rv[4] = {r4.x, r4.y, r4.z, r4.w};
            const float iv[4] = {i4.x, i4.y, i4.z, i4.w};
#pragma unroll
            for (int j = 0; j < 4; ++j) {
                s[0][j] += rv[j];
                s[1][j] += iv[j];
                s[2][j] += rv[j] * iv[j];
                s[3][j] += rv[j] * rv[j];
            }
        }
    }

    for (int y = y0; y < y0 + SH; ++y) {
        const int buf = y & 1;

        // thread-local inclusive scan + wave scan per field
        float ps[4][4], tot[4], wsc[4];
#pragma unroll
        for (int f = 0; f < 4; ++f) {
            ps[f][0] = s[f][0];
            ps[f][1] = ps[f][0] + s[f][1];
            ps[f][2] = ps[f][1] + s[f][2];
            ps[f][3] = ps[f][2] + s[f][3];
            tot[f] = ps[f][3];
            float v = tot[f];
#pragma unroll
            for (int d = 1; d < 64; d <<= 1) {
                const float t = __shfl_up(v, d, 64);
                if (lane >= d) v += t;
            }
            wsc[f] = v;
            if (lane == 63) wt[buf][f][wid] = v;
        }
        __syncthreads();

#pragma unroll
        for (int f = 0; f < 4; ++f) {
            float woff = 0.0f;
#pragma unroll
            for (int w = 0; w < 4; ++w)
                if (w < wid) woff += wt[buf][f][w];
            const float ex = woff + wsc[f] - tot[f];  // exclusive prefix at x0
#pragma unroll
            for (int j = 0; j < 4; ++j)
                P[buf][f][padidx(x0 + 1 + j)] = ex + ps[f][j];
        }
        if (tid == 0) {
#pragma unroll
            for (int f = 0; f < 4; ++f) P[buf][f][0] = 0.0f;  // padidx(0)==0
        }
        __syncthreads();

        const float icy = 1.0f / (float)(min(y + RAD, H_ - 1) - max(y - RAD, 0) + 1);
        float av[4], bvv[4];
#pragma unroll
        for (int j = 0; j < 4; ++j) {
            const int x = x0 + j;
            const int hi = padidx(min(x + RAD + 1, W_));
            const int lo = padidx(max(x - RAD, 0));
            const float SR = P[buf][0][hi] - P[buf][0][lo];
            const float SI = P[buf][1][hi] - P[buf][1][lo];
            const float SP = P[buf][2][hi] - P[buf][2][lo];
            const float SQ = P[buf][3][hi] - P[buf][3][lo];
            const float invN = icx[j] * icy;
            const float mR = SR * invN, mI = SI * invN;
            const float a = (SP * invN - mR * mI) / (SQ * invN - mR * mR + EPSF);
            av[j] = a;
            bvv[j] = mI - a * mR;
        }
        const long long ob = pb + (long long)y * W_ + x0;
        *(float4*)(A + ob)  = make_float4(av[0], av[1], av[2], av[3]);
        *(float4*)(Bv + ob) = make_float4(bvv[0], bvv[1], bvv[2], bvv[3]);

        // slide the vertical window
        const int ya = y + RAD + 1, ys = y - RAD;
        if (ya < H_) {
            const float4 r4 = *(const float4*)(R + ib + (long long)ya * W_ + x0);
            const float4 i4 = *(const float4*)(I + ib + (long long)ya * W_ + x0);
            const float rv[4] = {r4.x, r4.y, r4.z, r4.w};
            const float iv[4] = {i4.x, i4.y, i4.z, i4.w};
#pragma unroll
            for (int j = 0; j < 4; ++j) {
                s[0][j] += rv[j];
                s[1][j] += iv[j];
                s[2][j] += rv[j] * iv[j];
                s[3][j] += rv[j] * rv[j];
            }
        }
        if (ys >= 0) {
            const float4 r4 = *(const float4*)(R + ib + (long long)ys * W_ + x0);
            const float4 i4 = *(const float4*)(I + ib + (long long)ys * W_ + x0);
            const float rv[4] = {r4.x, r4.y, r4.z, r4.w};
            const float iv[4] = {i4.x, i4.y, i4.z, i4.w};
#pragma unroll
            for (int j = 0; j < 4; ++j) {
                s[0][j] -= rv[j];
                s[1][j] -= iv[j];
                s[2][j] -= rv[j] * iv[j];
                s[3][j] -= rv[j] * rv[j];
            }
        }
    }
}

// ---------------------------------------------------------------------------
// fused_cd: same walking structure over fields {a, b}; box means of a, b;
// out = mean_a * R + mean_b.
// ---------------------------------------------------------------------------
__global__ __launch_bounds__(256)
void fused_cd(const float* __restrict__ A, const float* __restrict__ Bv,
              const float* __restrict__ Rimg, long long in_off,
              float* __restrict__ out)
{
    __shared__ float P[2][2][PSZ];
    __shared__ float wt[2][2][4];

    const int tid = threadIdx.x;
    const int lane = tid & 63, wid = tid >> 6;
    const int x0 = tid * 4;
    const int y0 = blockIdx.x * SH;
    const long long pb = (long long)blockIdx.y * (long long)(H_ * W_);
    const long long ib = in_off + pb;

    float icx[4];
#pragma unroll
    for (int j = 0; j < 4; ++j) {
        const int x = x0 + j;
        icx[j] = 1.0f / (float)(min(x + RAD, W_ - 1) - max(x - RAD, 0) + 1);
    }

    float s[2][4];
#pragma unroll
    for (int f = 0; f < 2; ++f)
#pragma unroll
        for (int j = 0; j < 4; ++j) s[f][j] = 0.0f;

    {
        const int ylo = max(0, y0 - RAD), yhi = min(H_ - 1, y0 + RAD);
        for (int yy = ylo; yy <= yhi; ++yy) {
            const float4 a4 = *(const float4*)(A + pb + (long long)yy * W_ + x0);
            const float4 b4 = *(const float4*)(Bv + pb + (long long)yy * W_ + x0);
            const float av[4] = {a4.x, a4.y, a4.z, a4.w};
            const float bv[4] = {b4.x, b4.y, b4.z, b4.w};
#pragma unroll
            for (int j = 0; j < 4; ++j) { s[0][j] += av[j]; s[1][j] += bv[j]; }
        }
    }

    for (int y = y0; y < y0 + SH; ++y) {
        const int buf = y & 1;

        float ps[2][4], tot[2], wsc[2];
#pragma unroll
        for (int f = 0; f < 2; ++f) {
            ps[f][0] = s[f][0];
            ps[f][1] = ps[f][0] + s[f][1];
            ps[f][2] = ps[f][1] + s[f][2];
            ps[f][3] = ps[f][2] + s[f][3];
            tot[f] = ps[f][3];
            float v = tot[f];
#pragma unroll
            for (int d = 1; d < 64; d <<= 1) {
                const float t = __shfl_up(v, d, 64);
                if (lane >= d) v += t;
            }
            wsc[f] = v;
            if (lane == 63) wt[buf][f][wid] = v;
        }
        __syncthreads();

#pragma unroll
        for (int f = 0; f < 2; ++f) {
            float woff = 0.0f;
#pragma unroll
            for (int w = 0; w < 4; ++w)
                if (w < wid) woff += wt[buf][f][w];
            const float ex = woff + wsc[f] - tot[f];
#pragma unroll
            for (int j = 0; j < 4; ++j)
                P[buf][f][padidx(x0 + 1 + j)] = ex + ps[f][j];
        }
        if (tid == 0) {
            P[buf][0][0] = 0.0f;
            P[buf][1][0] = 0.0f;
        }
        __syncthreads();

        const float icy = 1.0f / (float)(min(y + RAD, H_ - 1) - max(y - RAD, 0) + 1);
        const long long og = ib + (long long)y * W_ + x0;
        const float4 r4 = *(const float4*)(Rimg + og);
        const float rv[4] = {r4.x, r4.y, r4.z, r4.w};
        float ov[4];
#pragma unroll
        for (int j = 0; j < 4; ++j) {
            const int x = x0 + j;
            const int hi = padidx(min(x + RAD + 1, W_));
            const int lo = padidx(max(x - RAD, 0));
            const float SA = P[buf][0][hi] - P[buf][0][lo];
            const float SB = P[buf][1][hi] - P[buf][1][lo];
            const float invN = icx[j] * icy;
            ov[j] = (SA * invN) * rv[j] + SB * invN;
        }
        *(float4*)(out + og) = make_float4(ov[0], ov[1], ov[2], ov[3]);

        const int ya = y + RAD + 1, ys = y - RAD;
        if (ya < H_) {
            const float4 a4 = *(const float4*)(A + pb + (long long)ya * W_ + x0);
            const float4 b4 = *(const float4*)(Bv + pb + (long long)ya * W_ + x0);
            const float av[4] = {a4.x, a4.y, a4.z, a4.w};
            const float bv[4] = {b4.x, b4.y, b4.z, b4.w};
#pragma unroll
            for (int j = 0; j < 4; ++j) { s[0][j] += av[j]; s[1][j] += bv[j]; }
        }
        if (ys >= 0) {
            const float4 a4 = *(const float4*)(A + pb + (long long)ys * W_ + x0);
            const float4 b4 = *(const float4*)(Bv + pb + (long long)ys * W_ + x0);
            const float av[4] = {a4.x, a4.y, a4.z, a4.w};
            const float bv[4] = {b4.x, b4.y, b4.z, b4.w};
#pragma unroll
            for (int j = 0; j < 4; ++j) { s[0][j] -= av[j]; s[1][j] -= bv[j]; }
        }
    }
}

// ---------------------------------------------------------------------------
extern "C" void kernel_launch(void* const* d_in, const int* in_sizes, int n_in,
                              void* d_out, int out_size, void* d_ws, size_t ws_size,
                              hipStream_t stream)
{
    const float* I = (const float*)d_in[0];   // image to filter
    const float* R = (const float*)d_in[1];   // guidance image
    float* out = (float*)d_out;

    const long long plane = (long long)H_ * W_;
    const int P_ = (int)(in_sizes[0] / plane);            // 24 planes
    const size_t arr_pb = (size_t)plane * sizeof(float);  // 4 MB/plane/array

    int CH = (int)(ws_size / (2 * arr_pb));   // only a, b live in scratch now
    if (CH > P_) CH = P_;
    if (CH < 1) CH = 1;

    float* A  = (float*)d_ws;
    float* Bv = A + (size_t)CH * plane;

    for (int p0 = 0; p0 < P_; p0 += CH) {
        const int pc = (P_ - p0 < CH) ? (P_ - p0) : CH;
        const long long in_off = (long long)p0 * plane;
        const dim3 g(NSEG, pc);

        hipLaunchKernelGGL(fused_ab, g, dim3(256), 0, stream,
                           I, R, in_off, A, Bv);
        hipLaunchKernelGGL(fused_cd, g, dim3(256), 0, stream,
                           A, Bv, R, in_off, out);
    }
}